// Round 4
// baseline (641.691 us; speedup 1.0000x reference)
//
#include <hip/hip_runtime.h>

#define MM 16384
#define NN 4096
#define KK 4096
#define BM 256
#define BN 256
#define BK 64
#define NT (KK / BK)   // 64 K-tiles

typedef __attribute__((ext_vector_type(8))) unsigned short u16x8;
typedef __attribute__((ext_vector_type(8))) short s16x8;
typedef __attribute__((ext_vector_type(4))) float f32x4;
typedef __attribute__((ext_vector_type(16))) float f32x16;

typedef __attribute__((address_space(1))) const void global_cvoid;
typedef __attribute__((address_space(3))) void lds_void;

__device__ __forceinline__ unsigned short f2bf(float f) {
    unsigned int u = __float_as_uint(f);
    u += 0x7fffu + ((u >> 16) & 1u);   // round-to-nearest-even
    return (unsigned short)(u >> 16);
}

__device__ __forceinline__ void lds_load16(const void* g, void* l) {
    __builtin_amdgcn_global_load_lds((global_cvoid*)g, (lds_void*)l, 16, 0, 0);
}

__device__ __forceinline__ void mfma16(f32x4& d, s16x8 a, s16x8 b) {
    d = __builtin_amdgcn_mfma_f32_16x16x32_bf16(a, b, d, 0, 0, 0);
}

__device__ __forceinline__ void mfma32(f32x16& d, s16x8 a, s16x8 b) {
    d = __builtin_amdgcn_mfma_f32_32x32x16_bf16(a, b, d, 0, 0, 0);
}

// ---- fused: W01[i01][j01][s2] (blocks 0..255) and W23L[j23][s2][i23] (256..511)
__global__ void k_build_w0123(const float* __restrict__ g0, const float* __restrict__ g1,
                              const float* __restrict__ g2, const float* __restrict__ g3,
                              float* __restrict__ w01, float* __restrict__ w23) {
    int b = blockIdx.x;
    int t = (b & 255) * 256 + threadIdx.x;            // 65536 each half
    if (b < 256) {
        int s2  = t & 15;
        int j01 = (t >> 4) & 63;
        int i01 = t >> 10;
        int i0 = i01 >> 3, i1 = i01 & 7, j0 = j01 >> 3, j1 = j01 & 7;
        float acc = 0.f;
#pragma unroll
        for (int s1 = 0; s1 < 16; ++s1)
            acc += g0[i0 * 128 + j0 * 16 + s1] * g1[s1 * 1024 + i1 * 128 + j1 * 16 + s2];
        w01[t] = acc;
    } else {
        int i23 = t & 63;
        int s2  = (t >> 6) & 15;
        int j23 = t >> 10;
        int i2 = i23 >> 3, i3 = i23 & 7, j2 = j23 >> 3, j3 = j23 & 7;
        float acc = 0.f;
#pragma unroll
        for (int s3 = 0; s3 < 16; ++s3)
            acc += g2[s2 * 1024 + i2 * 128 + j2 * 16 + s3] * g3[s3 * 64 + i3 * 8 + j3];
        w23[t] = acc;  // t == j23*1024 + s2*64 + i23  -> coalesced write
    }
}

// ---- standalone Wt build (fallback path only)
__global__ void k_build_wt(const float* __restrict__ w01, const float* __restrict__ w23,
                           unsigned short* __restrict__ wt) {
    unsigned int t = blockIdx.x * 256u + threadIdx.x; // 16,777,216
    int k = t & 4095;
    int n = t >> 12;
    int i01 = k >> 6, i23 = k & 63, j01 = n >> 6, j23 = n & 63;
    float acc = 0.f;
#pragma unroll
    for (int s2 = 0; s2 < 16; ++s2)
        acc += w01[i01 * 1024 + j01 * 16 + s2] * w23[j23 * 1024 + s2 * 64 + i23];
    wt[t] = f2bf(acc);
}

// ---- fused: x f32->bf16 convert (8 elems/thread) + Wt build (2 elems/thread).
__global__ void k_wt_convert(const float* __restrict__ w01, const float* __restrict__ w23,
                             unsigned short* __restrict__ wt,
                             const float* __restrict__ x, unsigned short* __restrict__ xb) {
    unsigned int T = blockIdx.x * 256u + threadIdx.x;  // 8,388,608
    size_t i = (size_t)T * 8;
    const float4* p = (const float4*)(x + i);
    float4 a = p[0], b = p[1];
    u16x8 o;
    o[0] = f2bf(a.x); o[1] = f2bf(a.y); o[2] = f2bf(a.z); o[3] = f2bf(a.w);
    o[4] = f2bf(b.x); o[5] = f2bf(b.y); o[6] = f2bf(b.z); o[7] = f2bf(b.w);
    *(u16x8*)(xb + i) = o;

    unsigned int t0 = T * 2u;
    int k = t0 & 4095;
    int n = t0 >> 12;
    int i01 = k >> 6, i23 = k & 63, j01 = n >> 6, j23 = n & 63;
    float acc0 = 0.f, acc1 = 0.f;
#pragma unroll
    for (int s2 = 0; s2 < 16; ++s2) {
        float wa = w01[i01 * 1024 + j01 * 16 + s2];
        const float* wb = w23 + j23 * 1024 + s2 * 64 + i23;
        acc0 += wa * wb[0];
        acc1 += wa * wb[1];
    }
    ((unsigned int*)wt)[T] = (unsigned int)f2bf(acc0) | ((unsigned int)f2bf(acc1) << 16);
}

// ============================================================================
// 256x256 GEMM — R11's verified 4-phase skeleton (490us/50.8%; R12/R13 both
// refuted schedule perturbations). R15 change: 16x16x32 -> 32x32x16 MFMA.
// Same FLOPs in 2066 cyc/CU/K-tile instead of 2483 (m119: 2495 vs 2075 TF
// ubench) and HALF the MFMA instruction count (8/phase vs 16). Staging,
// swizzle, barrier/vmcnt placement, phase->LDS-region map: byte-identical.
//   A-frag (32x32x16): row = lane&31, k = 8*(lane>>5)+i  (2xK gen of the
//   verified 16x16 pattern). C/D: col=lane&31, row=(reg&3)+8*(reg>>2)
//   +4*(lane>>5)  [m74/m101-verified].
// ds_read count unchanged (24 b128/wave/K-tile); per-quarter-wave bank-slot
// distribution identical to 16x16 version (2 lanes/16B slot) -> conflicts 0.
//   predict: gemm 483 -> ~430-455us, MfmaUtil ~flat, VALUBusy down slightly.
// ============================================================================
__global__ __launch_bounds__(512, 2) void k_gemm8(const unsigned short* __restrict__ A,
                                                  const unsigned short* __restrict__ Bt,
                                                  float* __restrict__ C,
                                                  const float* __restrict__ bias) {
    __shared__ unsigned short As[2][BM * BK];   // 2 x 32 KiB
    __shared__ unsigned short Bs[2][BN * BK];   // 2 x 32 KiB

    const int t = threadIdx.x;
    const int lane = t & 63;
    const int w = t >> 6;
    const int wm = w >> 2;        // 0..1
    const int wn = w & 3;         // 0..3

    const int mb = blockIdx.x >> 4;   // 64 m-tiles
    const int nb = blockIdx.x & 15;   // 16 n-tiles
    const int m0 = mb * BM, n0 = nb * BN;

    // --- staging precompute: load-unit v = t + u*512 covers one half-tile (16KB)
    // dest LDS byte linear in v (wave-uniform base + lane*16): OK for gload_lds.
    // source col-byte = dest-col-byte ^ ((row&7)<<4)  (inverse swizzle)
    // stage regions: A.mq0 = rows {0-63, 128-191} (both waves' first halves),
    // A.mq1 = rows {64-127, 192-255}; B.nq0 = first 32 cols of each 64-col
    // wave region, B.nq1 = second 32. Matches phase reads exactly (P0: first
    // halves + nq0; P1: nq1; P2: second halves; P3: -).
    const unsigned short* gA[2];
    const unsigned short* gB[2];
    int ldsA[2], ldsB[2];
#pragma unroll
    for (int u = 0; u < 2; ++u) {
        int v = t + u * 512;
        int rowA = (v >> 9) * 128 + ((v & 511) >> 3);
        int cbA = ((v & 7) * 16) ^ ((rowA & 7) << 4);
        gA[u] = A + (size_t)(m0 + rowA) * KK + (cbA >> 1);
        ldsA[u] = rowA * 64 + (v & 7) * 8;
        int rowB = (v >> 8) * 64 + ((v & 255) >> 3);
        int cbB = ((v & 7) * 16) ^ ((rowB & 7) << 4);
        gB[u] = Bt + (size_t)(n0 + rowB) * KK + (cbB >> 1);
        ldsB[u] = rowB * 64 + (v & 7) * 8;
    }

    auto stageA = [&](int tile, int mq, int bsel) {
        int tt = tile < NT ? tile : NT - 1;   // clamp: tail re-stages are idempotent
#pragma unroll
        for (int u = 0; u < 2; ++u)
            lds_load16(gA[u] + (size_t)mq * 64 * KK + tt * 64,
                       &As[bsel][mq * 4096 + ldsA[u]]);
    };
    auto stageB = [&](int tile, int nq, int bsel) {
        int tt = tile < NT ? tile : NT - 1;
#pragma unroll
        for (int u = 0; u < 2; ++u)
            lds_load16(gB[u] + (size_t)nq * 32 * KK + tt * 64,
                       &Bs[bsel][nq * 2048 + ldsB[u]]);
    };

    // --- ds_read swizzled offsets for 32x32x16 frags (ushort units)
    // row = base + (lane&31); k-bytes = ks*32 + (lane>>5)*16, XOR (row&7)<<4
    const int l31 = lane & 31;
    const int hi = lane >> 5;
    const int sw = (lane & 7) << 4;
    int ke[4];
#pragma unroll
    for (int ks = 0; ks < 4; ++ks)
        ke[ks] = ((ks * 32 + hi * 16) ^ sw) >> 1;

    const int arow = wm * 128 + l31;   // A LDS row for this lane
    const int brow = wn * 64 + l31;    // B LDS row for this lane

    f32x16 acc[4][2];
#pragma unroll
    for (int i = 0; i < 4; ++i)
#pragma unroll
        for (int j = 0; j < 2; ++j) {
            f32x16 z = {0.f, 0.f, 0.f, 0.f, 0.f, 0.f, 0.f, 0.f,
                        0.f, 0.f, 0.f, 0.f, 0.f, 0.f, 0.f, 0.f};
            acc[i][j] = z;
        }

    s16x8 aF[2][4], bF0[4], bF1[4];

    // K-tile body; bf is always a literal (loop unrolled by 2) so LDS bases fold
    auto KTILE = [&](int ti, int bf) {
        const unsigned short* pA = &As[bf][arow * 64];
        const unsigned short* pB = &Bs[bf][brow * 64];

        // ---- P0: reads A first-half (mt0,mt1 x 4ks = 8) + B.nt0 (4)
        //      | stage t+1 A.mq1 -> buf^1
#pragma unroll
        for (int mt = 0; mt < 2; ++mt)
#pragma unroll
            for (int ks = 0; ks < 4; ++ks)
                aF[mt][ks] = *(const s16x8*)(pA + mt * 2048 + ke[ks]);
#pragma unroll
        for (int ks = 0; ks < 4; ++ks)
            bF0[ks] = *(const s16x8*)(pB + ke[ks]);
        stageA(ti + 1, 1, bf ^ 1);
        __builtin_amdgcn_s_barrier();
        __builtin_amdgcn_s_setprio(1);
#pragma unroll
        for (int ks = 0; ks < 4; ++ks)
#pragma unroll
            for (int mt = 0; mt < 2; ++mt)
                mfma32(acc[mt][0], aF[mt][ks], bF0[ks]);
        __builtin_amdgcn_s_setprio(0);

        // ---- P1: reads B.nt1 (4) | stage t+2 A.mq0 -> cur buf
#pragma unroll
        for (int ks = 0; ks < 4; ++ks)
            bF1[ks] = *(const s16x8*)(pB + 2048 + ke[ks]);
        stageA(ti + 2, 0, bf);
        __builtin_amdgcn_s_barrier();
        __builtin_amdgcn_s_setprio(1);
#pragma unroll
        for (int ks = 0; ks < 4; ++ks)
#pragma unroll
            for (int mt = 0; mt < 2; ++mt)
                mfma32(acc[mt][1], aF[mt][ks], bF1[ks]);
        __builtin_amdgcn_s_setprio(0);

        // ---- P2: reads A second-half (8) | stage t+2 B.nq0 -> cur buf
#pragma unroll
        for (int mt = 0; mt < 2; ++mt)
#pragma unroll
            for (int ks = 0; ks < 4; ++ks)
                aF[mt][ks] = *(const s16x8*)(pA + 4096 + mt * 2048 + ke[ks]);
        stageB(ti + 2, 0, bf);
        __builtin_amdgcn_s_barrier();
        __builtin_amdgcn_s_setprio(1);
#pragma unroll
        for (int ks = 0; ks < 4; ++ks)
#pragma unroll
            for (int mt = 0; mt < 2; ++mt)
                mfma32(acc[2 + mt][0], aF[mt][ks], bF0[ks]);
        __builtin_amdgcn_s_setprio(0);

        // ---- P3: stage t+2 B.nq1 -> cur buf | vmcnt(6): tile t+1 fully landed
        stageB(ti + 2, 1, bf);
        asm volatile("s_waitcnt vmcnt(6)" ::: "memory");
        __builtin_amdgcn_s_barrier();
        __builtin_amdgcn_s_setprio(1);
#pragma unroll
        for (int ks = 0; ks < 4; ++ks)
#pragma unroll
            for (int mt = 0; mt < 2; ++mt)
                mfma32(acc[2 + mt][1], aF[mt][ks], bF1[ks]);
        __builtin_amdgcn_s_setprio(0);
    };

    // --- prologue: tile0 (4 halves) + tile1 {A.mq0, B.nq0, B.nq1} -> vmcnt(6)
    // leaves exactly tile1's 6 loads outstanding = steady-state invariant
    stageA(0, 0, 0); stageB(0, 0, 0); stageB(0, 1, 0); stageA(0, 1, 0);
    stageA(1, 0, 1); stageB(1, 0, 1); stageB(1, 1, 1);
    asm volatile("s_waitcnt vmcnt(6)" ::: "memory");
    __builtin_amdgcn_s_barrier();

    for (int ti = 0; ti < NT; ti += 2) {
        KTILE(ti, 0);
        KTILE(ti + 1, 1);
    }

    asm volatile("s_waitcnt vmcnt(0)" ::: "memory");
    __builtin_amdgcn_s_barrier();

    // ---- epilogue: 32x32 C/D layout: col = lane&31, row = (r&3)+8*(r>>2)
    //      +4*(lane>>5); per (am,an) tile, 4 reg-quads of 4 consecutive rows.
    const float bias_v = bias[0];
#pragma unroll
    for (int am = 0; am < 4; ++am) {
        const int growb = m0 + wm * 128 + am * 32 + hi * 4;
#pragma unroll
        for (int an = 0; an < 2; ++an) {
            const int gcol = n0 + wn * 64 + an * 32 + l31;
            f32x16 v = acc[am][an];
#pragma unroll
            for (int q = 0; q < 4; ++q) {
                float* cp = C + (size_t)(growb + q * 8) * NN + gcol;
#pragma unroll
                for (int rr = 0; rr < 4; ++rr) {
                    float o = v[q * 4 + rr] + bias_v;
                    __builtin_nontemporal_store(o > 0.f ? o : 0.f, cp + (size_t)rr * NN);
                }
            }
        }
    }
}

// ---- fallback 128^2 GEMM (f32 A converted in-register) for small-ws path
__global__ __launch_bounds__(256) void k_gemm_fb(const float* __restrict__ Af,
                                                 const unsigned short* __restrict__ Bt,
                                                 float* __restrict__ C,
                                                 const float* __restrict__ bias) {
    __shared__ unsigned short As[2][128 * 32];
    __shared__ unsigned short Bs[2][128 * 32];

    const int t = threadIdx.x;
    const int l = t & 63;
    const int w = t >> 6;
    const int wm = w >> 1, wn = w & 1;
    const int lrow = l & 15, lk = l >> 4;

    const int nb = blockIdx.x & 31;
    const int mb = blockIdx.x >> 5;
    const int m0 = mb * 128, n0 = nb * 128;

    f32x4 acc[4][4];
#pragma unroll
    for (int i = 0; i < 4; ++i)
#pragma unroll
        for (int j = 0; j < 4; ++j) {
            f32x4 z = {0.f, 0.f, 0.f, 0.f};
            acc[i][j] = z;
        }

    auto stageB = [&](int kt, int buf) {
#pragma unroll
        for (int q = 0; q < 2; ++q) {
            int c = w * 2 + q;
            int row = c * 16 + (l >> 2);
            int kc = (l & 3) * 8;
            const unsigned short* g = Bt + (size_t)(n0 + row) * KK + kt * 32 + kc;
            lds_load16(g, &Bs[buf][c * 512 + l * 8]);
        }
    };
    auto stageA = [&](int kt, int buf) {
        int row = t >> 1;
        int kh = (t & 1) * 16;
        const float4* g = (const float4*)(Af + (size_t)(m0 + row) * KK + kt * 32 + kh);
        float4 v0 = g[0], v1 = g[1], v2 = g[2], v3 = g[3];
        u16x8 o0, o1;
        o0[0] = f2bf(v0.x); o0[1] = f2bf(v0.y); o0[2] = f2bf(v0.z); o0[3] = f2bf(v0.w);
        o0[4] = f2bf(v1.x); o0[5] = f2bf(v1.y); o0[6] = f2bf(v1.z); o0[7] = f2bf(v1.w);
        o1[0] = f2bf(v2.x); o1[1] = f2bf(v2.y); o1[2] = f2bf(v2.z); o1[3] = f2bf(v2.w);
        o1[4] = f2bf(v3.x); o1[5] = f2bf(v3.y); o1[6] = f2bf(v3.z); o1[7] = f2bf(v3.w);
        *(u16x8*)&As[buf][row * 32 + kh] = o0;
        *(u16x8*)&As[buf][row * 32 + kh + 8] = o1;
    };

    stageA(0, 0);
    stageB(0, 0);

    const int NK = KK / 32;
    for (int kt = 0; kt < NK; ++kt) {
        __syncthreads();
        if (kt + 1 < NK) {
            stageA(kt + 1, (kt + 1) & 1);
            stageB(kt + 1, (kt + 1) & 1);
        }
        const int buf = kt & 1;
        const unsigned short* Ab = &As[buf][(wm * 64 + lrow) * 32 + lk * 8];
        const unsigned short* Bb = &Bs[buf][(wn * 64 + lrow) * 32 + lk * 8];
        s16x8 af[4], bfr[4];
#pragma unroll
        for (int i = 0; i < 4; ++i) af[i] = *(const s16x8*)(Ab + i * 16 * 32);
#pragma unroll
        for (int i = 0; i < 4; ++i) bfr[i] = *(const s16x8*)(Bb + i * 16 * 32);
#pragma unroll
        for (int i = 0; i < 4; ++i)
#pragma unroll
            for (int j = 0; j < 4; ++j) mfma16(acc[i][j], af[i], bfr[j]);
    }

    const float bias_v = bias[0];
    float* Cbase = C + (size_t)m0 * NN + n0;
#pragma unroll
    for (int mi = 0; mi < 4; ++mi) {
        int row0 = wm * 64 + mi * 16 + lk * 4;
#pragma unroll
        for (int ni = 0; ni < 4; ++ni) {
            int col = wn * 64 + ni * 16 + lrow;
            f32x4 v = acc[mi][ni];
#pragma unroll
            for (int r = 0; r < 4; ++r) {
                float o = v[r] + bias_v;
                Cbase[(size_t)(row0 + r) * NN + col] = o > 0.f ? o : 0.f;
            }
        }
    }
}

extern "C" void kernel_launch(void* const* d_in, const int* in_sizes, int n_in,
                              void* d_out, int out_size, void* d_ws, size_t ws_size,
                              hipStream_t stream) {
    const float* x  = (const float*)d_in[0];
    const float* g0 = (const float*)d_in[1];
    const float* g1 = (const float*)d_in[2];
    const float* g2 = (const float*)d_in[3];
    const float* g3 = (const float*)d_in[4];
    const float* bv = (const float*)d_in[5];
    float* out = (float*)d_out;
    char* ws = (char*)d_ws;

    unsigned short* wt = (unsigned short*)(ws);                         // 32 MiB bf16
    float* w01 = (float*)(ws + 33554432);                               // 256 KiB
    float* w23 = (float*)(ws + 33554432 + 262144);                     // 256 KiB
    unsigned short* xb = (unsigned short*)(ws + 34078720);             // 128 MiB bf16
    const size_t need_full = 34078720ull + (size_t)MM * KK * 2;

    k_build_w0123<<<dim3(512), dim3(256), 0, stream>>>(g0, g1, g2, g3, w01, w23);

    if (ws_size >= need_full) {
        k_wt_convert<<<dim3(32768), dim3(256), 0, stream>>>(w01, w23, wt, x, xb);
        k_gemm8<<<dim3((MM / BM) * (NN / BN)), dim3(512), 0, stream>>>(xb, wt, out, bv);
    } else {
        k_build_wt<<<dim3(65536), dim3(256), 0, stream>>>(w01, w23, wt);
        k_gemm_fb<<<dim3((MM / 128) * (NN / 128)), dim3(256), 0, stream>>>(x, wt, out, bv);
    }
}

// Round 5
// 582.352 us; speedup vs baseline: 1.1019x; 1.1019x over previous
//
#include <hip/hip_runtime.h>

#define MM 16384
#define NN 4096
#define KK 4096
#define BM 256
#define BN 256
#define BK 64
#define NT (KK / BK)   // 64 K-tiles

typedef __attribute__((ext_vector_type(8))) unsigned short u16x8;
typedef __attribute__((ext_vector_type(8))) short s16x8;
typedef __attribute__((ext_vector_type(4))) float f32x4;

typedef __attribute__((address_space(1))) const void global_cvoid;
typedef __attribute__((address_space(3))) void lds_void;

__device__ __forceinline__ unsigned short f2bf(float f) {
    unsigned int u = __float_as_uint(f);
    u += 0x7fffu + ((u >> 16) & 1u);   // round-to-nearest-even
    return (unsigned short)(u >> 16);
}

__device__ __forceinline__ void lds_load16(const void* g, void* l) {
    __builtin_amdgcn_global_load_lds((global_cvoid*)g, (lds_void*)l, 16, 0, 0);
}

__device__ __forceinline__ void mfma16(f32x4& d, s16x8 a, s16x8 b) {
    d = __builtin_amdgcn_mfma_f32_16x16x32_bf16(a, b, d, 0, 0, 0);
}

// ---- fused: W01[i01][j01][s2] (blocks 0..255) and W23L[j23][s2][i23] (256..511)
__global__ void k_build_w0123(const float* __restrict__ g0, const float* __restrict__ g1,
                              const float* __restrict__ g2, const float* __restrict__ g3,
                              float* __restrict__ w01, float* __restrict__ w23) {
    int b = blockIdx.x;
    int t = (b & 255) * 256 + threadIdx.x;            // 65536 each half
    if (b < 256) {
        int s2  = t & 15;
        int j01 = (t >> 4) & 63;
        int i01 = t >> 10;
        int i0 = i01 >> 3, i1 = i01 & 7, j0 = j01 >> 3, j1 = j01 & 7;
        float acc = 0.f;
#pragma unroll
        for (int s1 = 0; s1 < 16; ++s1)
            acc += g0[i0 * 128 + j0 * 16 + s1] * g1[s1 * 1024 + i1 * 128 + j1 * 16 + s2];
        w01[t] = acc;
    } else {
        int i23 = t & 63;
        int s2  = (t >> 6) & 15;
        int j23 = t >> 10;
        int i2 = i23 >> 3, i3 = i23 & 7, j2 = j23 >> 3, j3 = j23 & 7;
        float acc = 0.f;
#pragma unroll
        for (int s3 = 0; s3 < 16; ++s3)
            acc += g2[s2 * 1024 + i2 * 128 + j2 * 16 + s3] * g3[s3 * 64 + i3 * 8 + j3];
        w23[t] = acc;  // t == j23*1024 + s2*64 + i23  -> coalesced write
    }
}

// ---- standalone Wt build (fallback path only)
__global__ void k_build_wt(const float* __restrict__ w01, const float* __restrict__ w23,
                           unsigned short* __restrict__ wt) {
    unsigned int t = blockIdx.x * 256u + threadIdx.x; // 16,777,216
    int k = t & 4095;
    int n = t >> 12;
    int i01 = k >> 6, i23 = k & 63, j01 = n >> 6, j23 = n & 63;
    float acc = 0.f;
#pragma unroll
    for (int s2 = 0; s2 < 16; ++s2)
        acc += w01[i01 * 1024 + j01 * 16 + s2] * w23[j23 * 1024 + s2 * 64 + i23];
    wt[t] = f2bf(acc);
}

// ---- fused: x f32->bf16 convert (8 elems/thread) + Wt build (2 elems/thread).
// Convert is memory-bound (~384 MiB moved); wt's 32 fma/thread hides under it.
__global__ void k_wt_convert(const float* __restrict__ w01, const float* __restrict__ w23,
                             unsigned short* __restrict__ wt,
                             const float* __restrict__ x, unsigned short* __restrict__ xb) {
    unsigned int T = blockIdx.x * 256u + threadIdx.x;  // 8,388,608
    size_t i = (size_t)T * 8;
    const float4* p = (const float4*)(x + i);
    float4 a = p[0], b = p[1];
    u16x8 o;
    o[0] = f2bf(a.x); o[1] = f2bf(a.y); o[2] = f2bf(a.z); o[3] = f2bf(a.w);
    o[4] = f2bf(b.x); o[5] = f2bf(b.y); o[6] = f2bf(b.z); o[7] = f2bf(b.w);
    *(u16x8*)(xb + i) = o;

    unsigned int t0 = T * 2u;
    int k = t0 & 4095;
    int n = t0 >> 12;
    int i01 = k >> 6, i23 = k & 63, j01 = n >> 6, j23 = n & 63;
    float acc0 = 0.f, acc1 = 0.f;
#pragma unroll
    for (int s2 = 0; s2 < 16; ++s2) {
        float wa = w01[i01 * 1024 + j01 * 16 + s2];
        const float* wb = w23 + j23 * 1024 + s2 * 64 + i23;
        acc0 += wa * wb[0];
        acc1 += wa * wb[1];
    }
    ((unsigned int*)wt)[T] = (unsigned int)f2bf(acc0) | ((unsigned int)f2bf(acc1) << 16);
}

// ============================================================================
// 256x256 GEMM — R11's verified 4-phase skeleton (best: 483-490us / ~51%).
// R16 = exact revert to R14 after four refuted perturbations:
//   R12 XCD swizzle (FETCH unmoved), R12 split vmcnt (fence cost),
//   R13 t+2 self-buffer staging (slower), R15 32x32 MFMA (5e7 bank conflicts:
//   row=lane&31 fragment reads alias 4 lanes per post-swizzle 16B slot;
//   the 16-row pattern below aliases only 2-way, which is free -> conflicts 0).
// This 4-phase 16x16 structure is a verified local optimum in all four
// perturbation directions.
// ============================================================================
__global__ __launch_bounds__(512, 2) void k_gemm8(const unsigned short* __restrict__ A,
                                                  const unsigned short* __restrict__ Bt,
                                                  float* __restrict__ C,
                                                  const float* __restrict__ bias) {
    __shared__ unsigned short As[2][BM * BK];   // 2 x 32 KiB
    __shared__ unsigned short Bs[2][BN * BK];   // 2 x 32 KiB

    const int t = threadIdx.x;
    const int lane = t & 63;
    const int w = t >> 6;
    const int wm = w >> 2;        // 0..1
    const int wn = w & 3;         // 0..3

    const int mb = blockIdx.x >> 4;   // 64 m-tiles
    const int nb = blockIdx.x & 15;   // 16 n-tiles
    const int m0 = mb * BM, n0 = nb * BN;

    // --- staging precompute: load-unit v = t + u*512 covers one half-tile (16KB)
    // dest LDS byte linear in v (wave-uniform base + lane*16): OK for gload_lds.
    // source col-byte = dest-col-byte ^ ((row&7)<<4)  (inverse swizzle)
    const unsigned short* gA[2];
    const unsigned short* gB[2];
    int ldsA[2], ldsB[2];
#pragma unroll
    for (int u = 0; u < 2; ++u) {
        int v = t + u * 512;
        int rowA = (v >> 9) * 128 + ((v & 511) >> 3);
        int cbA = ((v & 7) * 16) ^ ((rowA & 7) << 4);
        gA[u] = A + (size_t)(m0 + rowA) * KK + (cbA >> 1);
        ldsA[u] = rowA * 64 + (v & 7) * 8;
        int rowB = (v >> 8) * 64 + ((v & 255) >> 3);
        int cbB = ((v & 7) * 16) ^ ((rowB & 7) << 4);
        gB[u] = Bt + (size_t)(n0 + rowB) * KK + (cbB >> 1);
        ldsB[u] = rowB * 64 + (v & 7) * 8;
    }

    auto stageA = [&](int tile, int mq, int bsel) {
        int tt = tile < NT ? tile : NT - 1;   // clamp: tail re-stages are idempotent
#pragma unroll
        for (int u = 0; u < 2; ++u)
            lds_load16(gA[u] + (size_t)mq * 64 * KK + tt * 64,
                       &As[bsel][mq * 4096 + ldsA[u]]);
    };
    auto stageB = [&](int tile, int nq, int bsel) {
        int tt = tile < NT ? tile : NT - 1;
#pragma unroll
        for (int u = 0; u < 2; ++u)
            lds_load16(gB[u] + (size_t)nq * 32 * KK + tt * 64,
                       &Bs[bsel][nq * 2048 + ldsB[u]]);
    };

    // --- ds_read swizzled offsets (ushort units)
    const int arb = wm * 128 + (lane & 15);
    const int brb = wn * 64 + (lane & 15);
    const int sw = (lane & 7) << 4;
    const int k0e = ((((lane >> 4) * 16)) ^ sw) >> 1;
    const int k1e = ((((lane >> 4) * 16) + 64) ^ sw) >> 1;

    f32x4 acc[8][4];
#pragma unroll
    for (int i = 0; i < 8; ++i)
#pragma unroll
        for (int j = 0; j < 4; ++j) {
            f32x4 z = {0.f, 0.f, 0.f, 0.f};
            acc[i][j] = z;
        }

    s16x8 a[4][2], b[2][2][2];

    // K-tile body; bf is always a literal (loop unrolled by 2) so LDS bases fold
    auto KTILE = [&](int ti, int bf) {
        const unsigned short* pA = &As[bf][arb * 64];
        const unsigned short* pB = &Bs[bf][brb * 64];

        // ---- P0: reads A.mq0 (8) + B.nq0 (4) | stage t+1 A.mq1 -> buf^1
#pragma unroll
        for (int mf = 0; mf < 4; ++mf) {
            a[mf][0] = *(const s16x8*)(pA + mf * 1024 + k0e);
            a[mf][1] = *(const s16x8*)(pA + mf * 1024 + k1e);
        }
#pragma unroll
        for (int nf = 0; nf < 2; ++nf) {
            b[0][nf][0] = *(const s16x8*)(pB + nf * 1024 + k0e);
            b[0][nf][1] = *(const s16x8*)(pB + nf * 1024 + k1e);
        }
        stageA(ti + 1, 1, bf ^ 1);
        __builtin_amdgcn_s_barrier();
        __builtin_amdgcn_s_setprio(1);
#pragma unroll
        for (int k = 0; k < 2; ++k)
#pragma unroll
            for (int mf = 0; mf < 4; ++mf)
#pragma unroll
                for (int nf = 0; nf < 2; ++nf)
                    mfma16(acc[mf][nf], a[mf][k], b[0][nf][k]);
        __builtin_amdgcn_s_setprio(0);

        // ---- P1: reads B.nq1 (4) | stage t+2 A.mq0 -> cur buf
#pragma unroll
        for (int nf = 0; nf < 2; ++nf) {
            b[1][nf][0] = *(const s16x8*)(pB + 2048 + nf * 1024 + k0e);
            b[1][nf][1] = *(const s16x8*)(pB + 2048 + nf * 1024 + k1e);
        }
        stageA(ti + 2, 0, bf);
        __builtin_amdgcn_s_barrier();
        __builtin_amdgcn_s_setprio(1);
#pragma unroll
        for (int k = 0; k < 2; ++k)
#pragma unroll
            for (int mf = 0; mf < 4; ++mf)
#pragma unroll
                for (int nf = 0; nf < 2; ++nf)
                    mfma16(acc[mf][2 + nf], a[mf][k], b[1][nf][k]);
        __builtin_amdgcn_s_setprio(0);

        // ---- P2: reads A.mq1 (8) | stage t+2 B.nq0 -> cur buf
#pragma unroll
        for (int mf = 0; mf < 4; ++mf) {
            a[mf][0] = *(const s16x8*)(pA + 4096 + mf * 1024 + k0e);
            a[mf][1] = *(const s16x8*)(pA + 4096 + mf * 1024 + k1e);
        }
        stageB(ti + 2, 0, bf);
        __builtin_amdgcn_s_barrier();
        __builtin_amdgcn_s_setprio(1);
#pragma unroll
        for (int k = 0; k < 2; ++k)
#pragma unroll
            for (int mf = 0; mf < 4; ++mf)
#pragma unroll
                for (int nf = 0; nf < 2; ++nf)
                    mfma16(acc[4 + mf][nf], a[mf][k], b[0][nf][k]);
        __builtin_amdgcn_s_setprio(0);

        // ---- P3: stage t+2 B.nq1 -> cur buf | vmcnt(6): tile t+1 fully landed
        stageB(ti + 2, 1, bf);
        asm volatile("s_waitcnt vmcnt(6)" ::: "memory");
        __builtin_amdgcn_s_barrier();
        __builtin_amdgcn_s_setprio(1);
#pragma unroll
        for (int k = 0; k < 2; ++k)
#pragma unroll
            for (int mf = 0; mf < 4; ++mf)
#pragma unroll
                for (int nf = 0; nf < 2; ++nf)
                    mfma16(acc[4 + mf][2 + nf], a[mf][k], b[1][nf][k]);
        __builtin_amdgcn_s_setprio(0);
    };

    // --- prologue: tile0 (4 halves) + tile1 {A.mq0, B.nq0, B.nq1} -> vmcnt(6)
    // leaves exactly tile1's 6 loads outstanding = steady-state invariant
    stageA(0, 0, 0); stageB(0, 0, 0); stageB(0, 1, 0); stageA(0, 1, 0);
    stageA(1, 0, 1); stageB(1, 0, 1); stageB(1, 1, 1);
    asm volatile("s_waitcnt vmcnt(6)" ::: "memory");
    __builtin_amdgcn_s_barrier();

    for (int ti = 0; ti < NT; ti += 2) {
        KTILE(ti, 0);
        KTILE(ti + 1, 1);
    }

    asm volatile("s_waitcnt vmcnt(0)" ::: "memory");
    __builtin_amdgcn_s_barrier();

    const float bias_v = bias[0];
    const int r0 = (lane >> 4) * 4;
    const int cc = lane & 15;
#pragma unroll
    for (int mf = 0; mf < 8; ++mf) {
        const int grow = m0 + wm * 128 + mf * 16 + r0;
#pragma unroll
        for (int nf = 0; nf < 4; ++nf) {
            const int gcol = n0 + wn * 64 + nf * 16 + cc;
            f32x4 v = acc[mf][nf];
            float* cp = C + (size_t)grow * NN + gcol;
#pragma unroll
            for (int r = 0; r < 4; ++r) {
                float o = v[r] + bias_v;
                __builtin_nontemporal_store(o > 0.f ? o : 0.f, cp + (size_t)r * NN);
            }
        }
    }
}

// ---- fallback 128^2 GEMM (f32 A converted in-register) for small-ws path
__global__ __launch_bounds__(256) void k_gemm_fb(const float* __restrict__ Af,
                                                 const unsigned short* __restrict__ Bt,
                                                 float* __restrict__ C,
                                                 const float* __restrict__ bias) {
    __shared__ unsigned short As[2][128 * 32];
    __shared__ unsigned short Bs[2][128 * 32];

    const int t = threadIdx.x;
    const int l = t & 63;
    const int w = t >> 6;
    const int wm = w >> 1, wn = w & 1;
    const int lrow = l & 15, lk = l >> 4;

    const int nb = blockIdx.x & 31;
    const int mb = blockIdx.x >> 5;
    const int m0 = mb * 128, n0 = nb * 128;

    f32x4 acc[4][4];
#pragma unroll
    for (int i = 0; i < 4; ++i)
#pragma unroll
        for (int j = 0; j < 4; ++j) {
            f32x4 z = {0.f, 0.f, 0.f, 0.f};
            acc[i][j] = z;
        }

    auto stageB = [&](int kt, int buf) {
#pragma unroll
        for (int q = 0; q < 2; ++q) {
            int c = w * 2 + q;
            int row = c * 16 + (l >> 2);
            int kc = (l & 3) * 8;
            const unsigned short* g = Bt + (size_t)(n0 + row) * KK + kt * 32 + kc;
            lds_load16(g, &Bs[buf][c * 512 + l * 8]);
        }
    };
    auto stageA = [&](int kt, int buf) {
        int row = t >> 1;
        int kh = (t & 1) * 16;
        const float4* g = (const float4*)(Af + (size_t)(m0 + row) * KK + kt * 32 + kh);
        float4 v0 = g[0], v1 = g[1], v2 = g[2], v3 = g[3];
        u16x8 o0, o1;
        o0[0] = f2bf(v0.x); o0[1] = f2bf(v0.y); o0[2] = f2bf(v0.z); o0[3] = f2bf(v0.w);
        o0[4] = f2bf(v1.x); o0[5] = f2bf(v1.y); o0[6] = f2bf(v1.z); o0[7] = f2bf(v1.w);
        o1[0] = f2bf(v2.x); o1[1] = f2bf(v2.y); o1[2] = f2bf(v2.z); o1[3] = f2bf(v2.w);
        o1[4] = f2bf(v3.x); o1[5] = f2bf(v3.y); o1[6] = f2bf(v3.z); o1[7] = f2bf(v3.w);
        *(u16x8*)&As[buf][row * 32 + kh] = o0;
        *(u16x8*)&As[buf][row * 32 + kh + 8] = o1;
    };

    stageA(0, 0);
    stageB(0, 0);

    const int NK = KK / 32;
    for (int kt = 0; kt < NK; ++kt) {
        __syncthreads();
        if (kt + 1 < NK) {
            stageA(kt + 1, (kt + 1) & 1);
            stageB(kt + 1, (kt + 1) & 1);
        }
        const int buf = kt & 1;
        const unsigned short* Ab = &As[buf][(wm * 64 + lrow) * 32 + lk * 8];
        const unsigned short* Bb = &Bs[buf][(wn * 64 + lrow) * 32 + lk * 8];
        s16x8 af[4], bfr[4];
#pragma unroll
        for (int i = 0; i < 4; ++i) af[i] = *(const s16x8*)(Ab + i * 16 * 32);
#pragma unroll
        for (int i = 0; i < 4; ++i) bfr[i] = *(const s16x8*)(Bb + i * 16 * 32);
#pragma unroll
        for (int i = 0; i < 4; ++i)
#pragma unroll
            for (int j = 0; j < 4; ++j) mfma16(acc[i][j], af[i], bfr[j]);
    }

    const float bias_v = bias[0];
    float* Cbase = C + (size_t)m0 * NN + n0;
#pragma unroll
    for (int mi = 0; mi < 4; ++mi) {
        int row0 = wm * 64 + mi * 16 + lk * 4;
#pragma unroll
        for (int ni = 0; ni < 4; ++ni) {
            int col = wn * 64 + ni * 16 + lrow;
            f32x4 v = acc[mi][ni];
#pragma unroll
            for (int r = 0; r < 4; ++r) {
                float o = v[r] + bias_v;
                Cbase[(size_t)(row0 + r) * NN + col] = o > 0.f ? o : 0.f;
            }
        }
    }
}

extern "C" void kernel_launch(void* const* d_in, const int* in_sizes, int n_in,
                              void* d_out, int out_size, void* d_ws, size_t ws_size,
                              hipStream_t stream) {
    const float* x  = (const float*)d_in[0];
    const float* g0 = (const float*)d_in[1];
    const float* g1 = (const float*)d_in[2];
    const float* g2 = (const float*)d_in[3];
    const float* g3 = (const float*)d_in[4];
    const float* bv = (const float*)d_in[5];
    float* out = (float*)d_out;
    char* ws = (char*)d_ws;

    unsigned short* wt = (unsigned short*)(ws);                         // 32 MiB bf16
    float* w01 = (float*)(ws + 33554432);                               // 256 KiB
    float* w23 = (float*)(ws + 33554432 + 262144);                     // 256 KiB
    unsigned short* xb = (unsigned short*)(ws + 34078720);             // 128 MiB bf16
    const size_t need_full = 34078720ull + (size_t)MM * KK * 2;

    k_build_w0123<<<dim3(512), dim3(256), 0, stream>>>(g0, g1, g2, g3, w01, w23);

    if (ws_size >= need_full) {
        k_wt_convert<<<dim3(32768), dim3(256), 0, stream>>>(w01, w23, wt, x, xb);
        k_gemm8<<<dim3((MM / BM) * (NN / BN)), dim3(512), 0, stream>>>(xb, wt, out, bv);
    } else {
        k_build_wt<<<dim3(65536), dim3(256), 0, stream>>>(w01, w23, wt);
        k_gemm_fb<<<dim3((MM / 128) * (NN / 128)), dim3(256), 0, stream>>>(x, wt, out, bv);
    }
}

// Round 6
// 576.981 us; speedup vs baseline: 1.1122x; 1.0093x over previous
//
#include <hip/hip_runtime.h>

#define MM 16384
#define NN 4096
#define KK 4096
#define BM 256
#define BN 256
#define BK 64
#define NT (KK / BK)   // 64 K-tiles

typedef __attribute__((ext_vector_type(8))) unsigned short u16x8;
typedef __attribute__((ext_vector_type(8))) short s16x8;
typedef __attribute__((ext_vector_type(4))) float f32x4;

typedef __attribute__((address_space(1))) const void global_cvoid;
typedef __attribute__((address_space(3))) void lds_void;

__device__ __forceinline__ unsigned short f2bf(float f) {
    unsigned int u = __float_as_uint(f);
    u += 0x7fffu + ((u >> 16) & 1u);   // round-to-nearest-even
    return (unsigned short)(u >> 16);
}

__device__ __forceinline__ void lds_load16(const void* g, void* l) {
    __builtin_amdgcn_global_load_lds((global_cvoid*)g, (lds_void*)l, 16, 0, 0);
}

__device__ __forceinline__ void mfma16(f32x4& d, s16x8 a, s16x8 b) {
    d = __builtin_amdgcn_mfma_f32_16x16x32_bf16(a, b, d, 0, 0, 0);
}

// ============================================================================
// R17 aux restructure (gemm untouched):
//   k_prep  = [w0123 build (512 blocks) + x f32->bf16 convert (32768 blocks)]
//             The two jobs are mutually independent (no intra-kernel dep);
//             w0123's ~18K fma hide entirely inside the BW-bound convert.
//   k_wt    = standalone Wt build (32MiB write, w01/w23 L2-resident): ~6us.
// Removes one serial launch + the 4us w0123 kernel from the critical path.
// ============================================================================
__global__ void k_prep(const float* __restrict__ g0, const float* __restrict__ g1,
                       const float* __restrict__ g2, const float* __restrict__ g3,
                       float* __restrict__ w01, float* __restrict__ w23,
                       const float* __restrict__ x, unsigned short* __restrict__ xb) {
    int b = blockIdx.x;
    if (b < 512) {
        int t = (b & 255) * 256 + threadIdx.x;            // 65536 each half
        if (b < 256) {
            // W01[i01][j01][s2] = sum_s1 G0[i0,j0,s1] * G1[s1,i1,j1,s2]
            int s2  = t & 15;
            int j01 = (t >> 4) & 63;
            int i01 = t >> 10;
            int i0 = i01 >> 3, i1 = i01 & 7, j0 = j01 >> 3, j1 = j01 & 7;
            float acc = 0.f;
#pragma unroll
            for (int s1 = 0; s1 < 16; ++s1)
                acc += g0[i0 * 128 + j0 * 16 + s1] * g1[s1 * 1024 + i1 * 128 + j1 * 16 + s2];
            w01[t] = acc;
        } else {
            // W23L[j23][s2][i23] = sum_s3 G2[s2,i2,j2,s3] * G3[s3,i3,j3]
            int i23 = t & 63;
            int s2  = (t >> 6) & 15;
            int j23 = t >> 10;
            int i2 = i23 >> 3, i3 = i23 & 7, j2 = j23 >> 3, j3 = j23 & 7;
            float acc = 0.f;
#pragma unroll
            for (int s3 = 0; s3 < 16; ++s3)
                acc += g2[s2 * 1024 + i2 * 128 + j2 * 16 + s3] * g3[s3 * 64 + i3 * 8 + j3];
            w23[t] = acc;  // t == j23*1024 + s2*64 + i23 -> coalesced write
        }
        return;
    }
    // ---- x f32 -> bf16, 8 elems/thread
    unsigned int T = (unsigned int)(b - 512) * 256u + threadIdx.x;  // 8,388,608
    size_t i = (size_t)T * 8;
    const float4* p = (const float4*)(x + i);
    float4 a = p[0], v = p[1];
    u16x8 o;
    o[0] = f2bf(a.x); o[1] = f2bf(a.y); o[2] = f2bf(a.z); o[3] = f2bf(a.w);
    o[4] = f2bf(v.x); o[5] = f2bf(v.y); o[6] = f2bf(v.z); o[7] = f2bf(v.w);
    *(u16x8*)(xb + i) = o;
}

// ---- Wt[n][k] (bf16) = sum_s2 W01[i01][j01][s2] * W23L[j23][s2][i23]
// 2 outputs/thread (paired u32 write); w01/w23 are 512KiB total -> L2-resident.
__global__ void k_wt(const float* __restrict__ w01, const float* __restrict__ w23,
                     unsigned short* __restrict__ wt) {
    unsigned int T = blockIdx.x * 256u + threadIdx.x;  // 8,388,608
    unsigned int t0 = T * 2u;
    int k = t0 & 4095;
    int n = t0 >> 12;
    int i01 = k >> 6, i23 = k & 63, j01 = n >> 6, j23 = n & 63;
    float acc0 = 0.f, acc1 = 0.f;
#pragma unroll
    for (int s2 = 0; s2 < 16; ++s2) {
        float wa = w01[i01 * 1024 + j01 * 16 + s2];
        const float* wb = w23 + j23 * 1024 + s2 * 64 + i23;
        acc0 += wa * wb[0];
        acc1 += wa * wb[1];
    }
    ((unsigned int*)wt)[T] = (unsigned int)f2bf(acc0) | ((unsigned int)f2bf(acc1) << 16);
}

// ---- fallback-path kernels (small-ws): unchanged
__global__ void k_build_w0123(const float* __restrict__ g0, const float* __restrict__ g1,
                              const float* __restrict__ g2, const float* __restrict__ g3,
                              float* __restrict__ w01, float* __restrict__ w23) {
    int b = blockIdx.x;
    int t = (b & 255) * 256 + threadIdx.x;
    if (b < 256) {
        int s2  = t & 15;
        int j01 = (t >> 4) & 63;
        int i01 = t >> 10;
        int i0 = i01 >> 3, i1 = i01 & 7, j0 = j01 >> 3, j1 = j01 & 7;
        float acc = 0.f;
#pragma unroll
        for (int s1 = 0; s1 < 16; ++s1)
            acc += g0[i0 * 128 + j0 * 16 + s1] * g1[s1 * 1024 + i1 * 128 + j1 * 16 + s2];
        w01[t] = acc;
    } else {
        int i23 = t & 63;
        int s2  = (t >> 6) & 15;
        int j23 = t >> 10;
        int i2 = i23 >> 3, i3 = i23 & 7, j2 = j23 >> 3, j3 = j23 & 7;
        float acc = 0.f;
#pragma unroll
        for (int s3 = 0; s3 < 16; ++s3)
            acc += g2[s2 * 1024 + i2 * 128 + j2 * 16 + s3] * g3[s3 * 64 + i3 * 8 + j3];
        w23[t] = acc;
    }
}

__global__ void k_build_wt(const float* __restrict__ w01, const float* __restrict__ w23,
                           unsigned short* __restrict__ wt) {
    unsigned int t = blockIdx.x * 256u + threadIdx.x; // 16,777,216
    int k = t & 4095;
    int n = t >> 12;
    int i01 = k >> 6, i23 = k & 63, j01 = n >> 6, j23 = n & 63;
    float acc = 0.f;
#pragma unroll
    for (int s2 = 0; s2 < 16; ++s2)
        acc += w01[i01 * 1024 + j01 * 16 + s2] * w23[j23 * 1024 + s2 * 64 + i23];
    wt[t] = f2bf(acc);
}

// ============================================================================
// 256x256 GEMM — R11's verified 4-phase skeleton (best: 481-493us / ~51.5%).
// BYTE-IDENTICAL to R16's gemm. Verified local optimum in four perturbation
// directions: R12 XCD swizzle (FETCH unmoved), R12 split vmcnt (fence cost),
// R13 t+2 self-buffer staging (slower), R15 32x32 MFMA (5e7 bank conflicts).
// ============================================================================
__global__ __launch_bounds__(512, 2) void k_gemm8(const unsigned short* __restrict__ A,
                                                  const unsigned short* __restrict__ Bt,
                                                  float* __restrict__ C,
                                                  const float* __restrict__ bias) {
    __shared__ unsigned short As[2][BM * BK];   // 2 x 32 KiB
    __shared__ unsigned short Bs[2][BN * BK];   // 2 x 32 KiB

    const int t = threadIdx.x;
    const int lane = t & 63;
    const int w = t >> 6;
    const int wm = w >> 2;        // 0..1
    const int wn = w & 3;         // 0..3

    const int mb = blockIdx.x >> 4;   // 64 m-tiles
    const int nb = blockIdx.x & 15;   // 16 n-tiles
    const int m0 = mb * BM, n0 = nb * BN;

    // --- staging precompute: load-unit v = t + u*512 covers one half-tile (16KB)
    // dest LDS byte linear in v (wave-uniform base + lane*16): OK for gload_lds.
    // source col-byte = dest-col-byte ^ ((row&7)<<4)  (inverse swizzle)
    const unsigned short* gA[2];
    const unsigned short* gB[2];
    int ldsA[2], ldsB[2];
#pragma unroll
    for (int u = 0; u < 2; ++u) {
        int v = t + u * 512;
        int rowA = (v >> 9) * 128 + ((v & 511) >> 3);
        int cbA = ((v & 7) * 16) ^ ((rowA & 7) << 4);
        gA[u] = A + (size_t)(m0 + rowA) * KK + (cbA >> 1);
        ldsA[u] = rowA * 64 + (v & 7) * 8;
        int rowB = (v >> 8) * 64 + ((v & 255) >> 3);
        int cbB = ((v & 7) * 16) ^ ((rowB & 7) << 4);
        gB[u] = Bt + (size_t)(n0 + rowB) * KK + (cbB >> 1);
        ldsB[u] = rowB * 64 + (v & 7) * 8;
    }

    auto stageA = [&](int tile, int mq, int bsel) {
        int tt = tile < NT ? tile : NT - 1;   // clamp: tail re-stages are idempotent
#pragma unroll
        for (int u = 0; u < 2; ++u)
            lds_load16(gA[u] + (size_t)mq * 64 * KK + tt * 64,
                       &As[bsel][mq * 4096 + ldsA[u]]);
    };
    auto stageB = [&](int tile, int nq, int bsel) {
        int tt = tile < NT ? tile : NT - 1;
#pragma unroll
        for (int u = 0; u < 2; ++u)
            lds_load16(gB[u] + (size_t)nq * 32 * KK + tt * 64,
                       &Bs[bsel][nq * 2048 + ldsB[u]]);
    };

    // --- ds_read swizzled offsets (ushort units)
    const int arb = wm * 128 + (lane & 15);
    const int brb = wn * 64 + (lane & 15);
    const int sw = (lane & 7) << 4;
    const int k0e = ((((lane >> 4) * 16)) ^ sw) >> 1;
    const int k1e = ((((lane >> 4) * 16) + 64) ^ sw) >> 1;

    f32x4 acc[8][4];
#pragma unroll
    for (int i = 0; i < 8; ++i)
#pragma unroll
        for (int j = 0; j < 4; ++j) {
            f32x4 z = {0.f, 0.f, 0.f, 0.f};
            acc[i][j] = z;
        }

    s16x8 a[4][2], b[2][2][2];

    // K-tile body; bf is always a literal (loop unrolled by 2) so LDS bases fold
    auto KTILE = [&](int ti, int bf) {
        const unsigned short* pA = &As[bf][arb * 64];
        const unsigned short* pB = &Bs[bf][brb * 64];

        // ---- P0: reads A.mq0 (8) + B.nq0 (4) | stage t+1 A.mq1 -> buf^1
#pragma unroll
        for (int mf = 0; mf < 4; ++mf) {
            a[mf][0] = *(const s16x8*)(pA + mf * 1024 + k0e);
            a[mf][1] = *(const s16x8*)(pA + mf * 1024 + k1e);
        }
#pragma unroll
        for (int nf = 0; nf < 2; ++nf) {
            b[0][nf][0] = *(const s16x8*)(pB + nf * 1024 + k0e);
            b[0][nf][1] = *(const s16x8*)(pB + nf * 1024 + k1e);
        }
        stageA(ti + 1, 1, bf ^ 1);
        __builtin_amdgcn_s_barrier();
        __builtin_amdgcn_s_setprio(1);
#pragma unroll
        for (int k = 0; k < 2; ++k)
#pragma unroll
            for (int mf = 0; mf < 4; ++mf)
#pragma unroll
                for (int nf = 0; nf < 2; ++nf)
                    mfma16(acc[mf][nf], a[mf][k], b[0][nf][k]);
        __builtin_amdgcn_s_setprio(0);

        // ---- P1: reads B.nq1 (4) | stage t+2 A.mq0 -> cur buf
#pragma unroll
        for (int nf = 0; nf < 2; ++nf) {
            b[1][nf][0] = *(const s16x8*)(pB + 2048 + nf * 1024 + k0e);
            b[1][nf][1] = *(const s16x8*)(pB + 2048 + nf * 1024 + k1e);
        }
        stageA(ti + 2, 0, bf);
        __builtin_amdgcn_s_barrier();
        __builtin_amdgcn_s_setprio(1);
#pragma unroll
        for (int k = 0; k < 2; ++k)
#pragma unroll
            for (int mf = 0; mf < 4; ++mf)
#pragma unroll
                for (int nf = 0; nf < 2; ++nf)
                    mfma16(acc[mf][2 + nf], a[mf][k], b[1][nf][k]);
        __builtin_amdgcn_s_setprio(0);

        // ---- P2: reads A.mq1 (8) | stage t+2 B.nq0 -> cur buf
#pragma unroll
        for (int mf = 0; mf < 4; ++mf) {
            a[mf][0] = *(const s16x8*)(pA + 4096 + mf * 1024 + k0e);
            a[mf][1] = *(const s16x8*)(pA + 4096 + mf * 1024 + k1e);
        }
        stageB(ti + 2, 0, bf);
        __builtin_amdgcn_s_barrier();
        __builtin_amdgcn_s_setprio(1);
#pragma unroll
        for (int k = 0; k < 2; ++k)
#pragma unroll
            for (int mf = 0; mf < 4; ++mf)
#pragma unroll
                for (int nf = 0; nf < 2; ++nf)
                    mfma16(acc[4 + mf][nf], a[mf][k], b[0][nf][k]);
        __builtin_amdgcn_s_setprio(0);

        // ---- P3: stage t+2 B.nq1 -> cur buf | vmcnt(6): tile t+1 fully landed
        stageB(ti + 2, 1, bf);
        asm volatile("s_waitcnt vmcnt(6)" ::: "memory");
        __builtin_amdgcn_s_barrier();
        __builtin_amdgcn_s_setprio(1);
#pragma unroll
        for (int k = 0; k < 2; ++k)
#pragma unroll
            for (int mf = 0; mf < 4; ++mf)
#pragma unroll
                for (int nf = 0; nf < 2; ++nf)
                    mfma16(acc[4 + mf][2 + nf], a[mf][k], b[1][nf][k]);
        __builtin_amdgcn_s_setprio(0);
    };

    // --- prologue: tile0 (4 halves) + tile1 {A.mq0, B.nq0, B.nq1} -> vmcnt(6)
    // leaves exactly tile1's 6 loads outstanding = steady-state invariant
    stageA(0, 0, 0); stageB(0, 0, 0); stageB(0, 1, 0); stageA(0, 1, 0);
    stageA(1, 0, 1); stageB(1, 0, 1); stageB(1, 1, 1);
    asm volatile("s_waitcnt vmcnt(6)" ::: "memory");
    __builtin_amdgcn_s_barrier();

    for (int ti = 0; ti < NT; ti += 2) {
        KTILE(ti, 0);
        KTILE(ti + 1, 1);
    }

    asm volatile("s_waitcnt vmcnt(0)" ::: "memory");
    __builtin_amdgcn_s_barrier();

    const float bias_v = bias[0];
    const int r0 = (lane >> 4) * 4;
    const int cc = lane & 15;
#pragma unroll
    for (int mf = 0; mf < 8; ++mf) {
        const int grow = m0 + wm * 128 + mf * 16 + r0;
#pragma unroll
        for (int nf = 0; nf < 4; ++nf) {
            const int gcol = n0 + wn * 64 + nf * 16 + cc;
            f32x4 v = acc[mf][nf];
            float* cp = C + (size_t)grow * NN + gcol;
#pragma unroll
            for (int r = 0; r < 4; ++r) {
                float o = v[r] + bias_v;
                __builtin_nontemporal_store(o > 0.f ? o : 0.f, cp + (size_t)r * NN);
            }
        }
    }
}

// ---- fallback 128^2 GEMM (f32 A converted in-register) for small-ws path
__global__ __launch_bounds__(256) void k_gemm_fb(const float* __restrict__ Af,
                                                 const unsigned short* __restrict__ Bt,
                                                 float* __restrict__ C,
                                                 const float* __restrict__ bias) {
    __shared__ unsigned short As[2][128 * 32];
    __shared__ unsigned short Bs[2][128 * 32];

    const int t = threadIdx.x;
    const int l = t & 63;
    const int w = t >> 6;
    const int wm = w >> 1, wn = w & 1;
    const int lrow = l & 15, lk = l >> 4;

    const int nb = blockIdx.x & 31;
    const int mb = blockIdx.x >> 5;
    const int m0 = mb * 128, n0 = nb * 128;

    f32x4 acc[4][4];
#pragma unroll
    for (int i = 0; i < 4; ++i)
#pragma unroll
        for (int j = 0; j < 4; ++j) {
            f32x4 z = {0.f, 0.f, 0.f, 0.f};
            acc[i][j] = z;
        }

    auto stageB = [&](int kt, int buf) {
#pragma unroll
        for (int q = 0; q < 2; ++q) {
            int c = w * 2 + q;
            int row = c * 16 + (l >> 2);
            int kc = (l & 3) * 8;
            const unsigned short* g = Bt + (size_t)(n0 + row) * KK + kt * 32 + kc;
            lds_load16(g, &Bs[buf][c * 512 + l * 8]);
        }
    };
    auto stageA = [&](int kt, int buf) {
        int row = t >> 1;
        int kh = (t & 1) * 16;
        const float4* g = (const float4*)(Af + (size_t)(m0 + row) * KK + kt * 32 + kh);
        float4 v0 = g[0], v1 = g[1], v2 = g[2], v3 = g[3];
        u16x8 o0, o1;
        o0[0] = f2bf(v0.x); o0[1] = f2bf(v0.y); o0[2] = f2bf(v0.z); o0[3] = f2bf(v0.w);
        o0[4] = f2bf(v1.x); o0[5] = f2bf(v1.y); o0[6] = f2bf(v1.z); o0[7] = f2bf(v1.w);
        o1[0] = f2bf(v2.x); o1[1] = f2bf(v2.y); o1[2] = f2bf(v2.z); o1[3] = f2bf(v2.w);
        o1[4] = f2bf(v3.x); o1[5] = f2bf(v3.y); o1[6] = f2bf(v3.z); o1[7] = f2bf(v3.w);
        *(u16x8*)&As[buf][row * 32 + kh] = o0;
        *(u16x8*)&As[buf][row * 32 + kh + 8] = o1;
    };

    stageA(0, 0);
    stageB(0, 0);

    const int NK = KK / 32;
    for (int kt = 0; kt < NK; ++kt) {
        __syncthreads();
        if (kt + 1 < NK) {
            stageA(kt + 1, (kt + 1) & 1);
            stageB(kt + 1, (kt + 1) & 1);
        }
        const int buf = kt & 1;
        const unsigned short* Ab = &As[buf][(wm * 64 + lrow) * 32 + lk * 8];
        const unsigned short* Bb = &Bs[buf][(wn * 64 + lrow) * 32 + lk * 8];
        s16x8 af[4], bfr[4];
#pragma unroll
        for (int i = 0; i < 4; ++i) af[i] = *(const s16x8*)(Ab + i * 16 * 32);
#pragma unroll
        for (int i = 0; i < 4; ++i) bfr[i] = *(const s16x8*)(Bb + i * 16 * 32);
#pragma unroll
        for (int i = 0; i < 4; ++i)
#pragma unroll
            for (int j = 0; j < 4; ++j) mfma16(acc[i][j], af[i], bfr[j]);
    }

    const float bias_v = bias[0];
    float* Cbase = C + (size_t)m0 * NN + n0;
#pragma unroll
    for (int mi = 0; mi < 4; ++mi) {
        int row0 = wm * 64 + mi * 16 + lk * 4;
#pragma unroll
        for (int ni = 0; ni < 4; ++ni) {
            int col = wn * 64 + ni * 16 + lrow;
            f32x4 v = acc[mi][ni];
#pragma unroll
            for (int r = 0; r < 4; ++r) {
                float o = v[r] + bias_v;
                Cbase[(size_t)(row0 + r) * NN + col] = o > 0.f ? o : 0.f;
            }
        }
    }
}

extern "C" void kernel_launch(void* const* d_in, const int* in_sizes, int n_in,
                              void* d_out, int out_size, void* d_ws, size_t ws_size,
                              hipStream_t stream) {
    const float* x  = (const float*)d_in[0];
    const float* g0 = (const float*)d_in[1];
    const float* g1 = (const float*)d_in[2];
    const float* g2 = (const float*)d_in[3];
    const float* g3 = (const float*)d_in[4];
    const float* bv = (const float*)d_in[5];
    float* out = (float*)d_out;
    char* ws = (char*)d_ws;

    unsigned short* wt = (unsigned short*)(ws);                         // 32 MiB bf16
    float* w01 = (float*)(ws + 33554432);                               // 256 KiB
    float* w23 = (float*)(ws + 33554432 + 262144);                     // 256 KiB
    unsigned short* xb = (unsigned short*)(ws + 34078720);             // 128 MiB bf16
    const size_t need_full = 34078720ull + (size_t)MM * KK * 2;

    if (ws_size >= need_full) {
        k_prep<<<dim3(512 + 32768), dim3(256), 0, stream>>>(g0, g1, g2, g3, w01, w23, x, xb);
        k_wt<<<dim3(32768), dim3(256), 0, stream>>>(w01, w23, wt);
        k_gemm8<<<dim3((MM / BM) * (NN / BN)), dim3(512), 0, stream>>>(xb, wt, out, bv);
    } else {
        k_build_w0123<<<dim3(512), dim3(256), 0, stream>>>(g0, g1, g2, g3, w01, w23);
        k_build_wt<<<dim3(65536), dim3(256), 0, stream>>>(w01, w23, wt);
        k_gemm_fb<<<dim3((MM / 128) * (NN / 128)), dim3(256), 0, stream>>>(x, wt, out, bv);
    }
}